// Round 6
// baseline (657.295 us; speedup 1.0000x reference)
//
#include <hip/hip_runtime.h>
#include <hip/hip_fp16.h>

// NLSPN deformable propagation, B=4, H=480, W=640, 18 steps.
// Round 6: persistent kernel via PLAIN launch + manual grid barrier (no
// cooperative API -> no capture issues). Descriptors pinned in registers:
//   sample = u32{rel i16 | wy u8 | wx u8} + fp16 ak  -> 14 regs/px, PXT=5.
// sched_barrier(0) between 4-sample groups caps transient VGPR pressure.
// Guards: no spill + occupancy*CU >= grid (co-residency for the barrier);
// otherwise 18-launch compact-streamed fallback (R5-validated, ~648 us).

#define HH 480
#define WW 640
#define BB 4
#define HWSZ (HH * WW)        // 307200
#define NPIX (BB * HWSZ)      // 1228800
#define PROP_T 18
#define SLACK 704             // slack floats each side of state buffers
#define NTHR 256
#define PXT 5
#define NBLK (NPIX / (NTHR * PXT))   // 960

struct f2u { float x, y; };   // 4-aligned pair load

__device__ __forceinline__ float fast_tanh(float x) {
    x = fminf(fmaxf(x, -15.0f), 15.0f);
    float e = __expf(2.0f * x);
    return __fdividef(e - 1.0f, e + 1.0f);
}

__device__ __forceinline__ float affinities(const float* gb, float inv_scale,
                                            float t[8]) {
    float ssum = 1e-4f;
#pragma unroll
    for (int j = 0; j < 8; ++j) {
        float v = fast_tanh(gb[(16 + j) * HWSZ]) * inv_scale;
        t[j] = v; ssum += fabsf(v);
    }
    ssum = fmaxf(ssum, 1.0f);
    float rs = __fdividef(1.0f, ssum);
    float asum = 0.0f;
#pragma unroll
    for (int j = 0; j < 8; ++j) { t[j] *= rs; asum += t[j]; }
    return 1.0f - asum;
}

// Compact descriptor (R4/R5 hardware-validated boundary folding).
__device__ __forceinline__ void make_desc(int y, int x, int k,
                                          float dy, float dx, float ak,
                                          unsigned& pk, unsigned short& akh) {
    float py = (float)(y + k / 3 - 1) + dy;
    float px = (float)(x + k % 3 - 1) + dx;
    float y0f = floorf(py), x0f = floorf(px);
    float wy = py - y0f, wx = px - x0f;
    int y0 = (int)y0f, x0 = (int)x0f;
    if (y0 == -1)                 { ak *= wy;        wy = 1.0f; }
    else if (y0 == HH - 1)        { ak *= 1.0f - wy; wy = 0.0f; }
    else if (y0 < -1 || y0 >= HH) { ak = 0.0f; }
    if (x0 == -1)                 { ak *= wx;        wx = 1.0f; }
    else if (x0 == WW - 1)        { ak *= 1.0f - wx; wx = 0.0f; }
    else if (x0 < -1 || x0 >= WW) { ak = 0.0f; }
    int rel;
    if (ak == 0.0f) {
        rel = 0; wy = 0.0f; wx = 0.0f;
    } else {
        int yc = min(max(y0, -1), HH - 1);
        int xc = min(max(x0, -1), WW - 1);
        rel = (yc - y) * WW + (xc - x);
        rel = min(max(rel, -32767), 32767);
    }
    unsigned uy = (unsigned)(int)(wy * 255.0f + 0.5f);
    unsigned ux = (unsigned)(int)(wx * 255.0f + 0.5f);
    pk  = ((unsigned)(unsigned short)(short)rel << 16) | (uy << 8) | ux;
    akh = __half_as_ushort(__float2half(ak));
}

__device__ __forceinline__ float sample_rel(const float* __restrict__ fp,
                                            unsigned pk, unsigned short akh,
                                            float acc) {
    int rel = (int)(short)(pk >> 16);
    float wy = (float)((pk >> 8) & 0xffu) * (1.0f / 255.0f);
    float wx = (float)(pk & 0xffu) * (1.0f / 255.0f);
    float ak = __half2float(__ushort_as_half(akh));
    const float* p = fp + rel;
    f2u r0 = *reinterpret_cast<const f2u*>(p);
    f2u r1 = *reinterpret_cast<const f2u*>(p + WW);
    float bot = ak * wy;
    float top = ak - bot;
    float omwx = 1.0f - wx;
    acc = fmaf(top * omwx, r0.x, acc);
    acc = fmaf(top * wx,   r0.y, acc);
    acc = fmaf(bot * omwx, r1.x, acc);
    acc = fmaf(bot * wx,   r1.y, acc);
    return acc;
}

// ---------------- one-time descriptor build (feeds both paths) ----------------
__global__ __launch_bounds__(NTHR) void precompute_kernel(
    const float* __restrict__ feat_init,
    const float* __restrict__ guid,
    const float* __restrict__ confidence,
    const float* __restrict__ feat_fix,
    const float* __restrict__ aff_scale,
    float* __restrict__ g0,               // state init (interior base of bufA)
    unsigned* __restrict__ pk1Arr,        // [NPIX][8] px-major
    unsigned short* __restrict__ akArr,   // [NPIX][8] px-major
    uint2* __restrict__ cfArr) {          // {aref fp16<<16|conf fp16, bits(m*ff)}
    const int pix = blockIdx.x * NTHR + threadIdx.x;
    const int b = pix / HWSZ;
    const int q = pix - b * HWSZ;
    const int y = q / WW;
    const int x = q - y * WW;
    const float* gb = guid + (size_t)b * 24 * HWSZ + q;

    float ff = feat_fix[pix];
    float m  = (ff > 0.0f) ? 1.0f : 0.0f;
    float km = 1.0f - m;
    float conf = km * confidence[pix] + m;
    float f0   = km * feat_init[pix] + m * ff;
    g0[pix] = f0 * conf;

    const float inv_scale = __fdividef(1.0f, aff_scale[0] + 1e-8f);
    float t[8];
    float aref = affinities(gb, inv_scale, t);
    uint2 cf;
    cf.x = ((unsigned)__half_as_ushort(__float2half(aref)) << 16)
         | (unsigned)__half_as_ushort(__float2half(conf));
    float mff = m * ff;
    cf.y = __float_as_uint(mff);
    cfArr[pix] = cf;

    unsigned pk[8];
    unsigned short akh[8];
#pragma unroll
    for (int n = 0; n < 8; ++n) {
        const int k = (n < 4) ? n : (n + 1);
        float dy = gb[(2 * n) * HWSZ];
        float dx = gb[(2 * n + 1) * HWSZ];
        make_desc(y, x, k, dy, dx, t[n], pk[n], akh[n]);
    }
    uint4* pd = reinterpret_cast<uint4*>(pk1Arr) + 2 * pix;
    pd[0] = make_uint4(pk[0], pk[1], pk[2], pk[3]);
    pd[1] = make_uint4(pk[4], pk[5], pk[6], pk[7]);
    uint4 kv;
    kv.x = (unsigned)akh[0] | ((unsigned)akh[1] << 16);
    kv.y = (unsigned)akh[2] | ((unsigned)akh[3] << 16);
    kv.z = (unsigned)akh[4] | ((unsigned)akh[5] << 16);
    kv.w = (unsigned)akh[6] | ((unsigned)akh[7] << 16);
    reinterpret_cast<uint4*>(akArr)[pix] = kv;
}

// ---------------- persistent kernel, manual grid barrier ----------------
__global__ __launch_bounds__(NTHR, 4) void persist_kernel(
    const unsigned* __restrict__ pk1Arr,
    const unsigned short* __restrict__ akArr,
    const uint2* __restrict__ cfArr,
    float* __restrict__ fA,
    float* __restrict__ fB,
    float* __restrict__ out,
    int* __restrict__ bar)     // zeroed counter; monotonic sense-free barrier
{
    const int base = blockIdx.x * (NTHR * PXT) + threadIdx.x;

    uint4 pka[PXT], pkb[PXT], akv[PXT];   // 12 regs/px pinned
    uint2 cfr[PXT];                       // 2 regs/px pinned

#pragma unroll
    for (int i = 0; i < PXT; ++i) {
        const int pix = base + i * NTHR;
        const uint4* pd = reinterpret_cast<const uint4*>(pk1Arr) + 2 * pix;
        pka[i] = pd[0];
        pkb[i] = pd[1];
        akv[i] = reinterpret_cast<const uint4*>(akArr)[pix];
        cfr[i] = cfArr[pix];
    }

#pragma unroll 1
    for (int t = 0; t < PROP_T; ++t) {
        const float* fin = (t & 1) ? fB : fA;
        float* fout = (t == PROP_T - 1) ? out : ((t & 1) ? fA : fB);
        const bool last = (t == PROP_T - 1);
#pragma unroll
        for (int i = 0; i < PXT; ++i) {
            const int pix = base + i * NTHR;
            const float* fp = fin + pix;
            unsigned c = cfr[i].x;
            float aref = __half2float(__ushort_as_half((unsigned short)(c >> 16)));
            float conf = __half2float(__ushort_as_half((unsigned short)(c & 0xffffu)));
            float acc = aref * fp[0];
            uint4 A = pka[i], B = pkb[i], K = akv[i];
            acc = sample_rel(fp, A.x, (unsigned short)(K.x & 0xffffu), acc);
            acc = sample_rel(fp, A.y, (unsigned short)(K.x >> 16),     acc);
            acc = sample_rel(fp, A.z, (unsigned short)(K.y & 0xffffu), acc);
            acc = sample_rel(fp, A.w, (unsigned short)(K.y >> 16),     acc);
            __builtin_amdgcn_sched_barrier(0);   // cap in-flight gather regs
            acc = sample_rel(fp, B.x, (unsigned short)(K.z & 0xffffu), acc);
            acc = sample_rel(fp, B.y, (unsigned short)(K.z >> 16),     acc);
            acc = sample_rel(fp, B.z, (unsigned short)(K.w & 0xffffu), acc);
            acc = sample_rel(fp, B.w, (unsigned short)(K.w >> 16),     acc);
            float mff = __uint_as_float(cfr[i].y);
            float km = (mff > 0.0f) ? 0.0f : 1.0f;
            float fnew = fmaf(km, acc, mff);        // f' = km*prop + m*ff
            fout[pix] = last ? fnew : conf * fnew;  // g' = f'*conf
            __builtin_amdgcn_sched_barrier(0);
        }

        if (!last) {
            // grid barrier: all step-t writes device-visible before step t+1
            __syncthreads();                       // block's stores drained
            if (threadIdx.x == 0) {
                __threadfence();                   // agent release (wb L2)
                atomicAdd(bar, 1);                 // device-scope
                const int target = (t + 1) * NBLK;
                while (__hip_atomic_load(bar, __ATOMIC_ACQUIRE,
                                         __HIP_MEMORY_SCOPE_AGENT) < target) {
                    __builtin_amdgcn_s_sleep(4);
                }
                __threadfence();                   // agent acquire (inv stale)
            }
            __syncthreads();
        }
    }
}

// ---------------- non-cooperative fallback (compact streamed) ----------------
__global__ __launch_bounds__(NTHR) void step_kernel(
    const float* __restrict__ fin,
    float* __restrict__ fout,
    const unsigned* __restrict__ pk1Arr,
    const unsigned short* __restrict__ akArr,
    const uint2* __restrict__ cfArr,
    int last) {
    const int pix = blockIdx.x * NTHR + threadIdx.x;
    const float* fp = fin + pix;
    const uint4* pd = reinterpret_cast<const uint4*>(pk1Arr) + 2 * pix;
    uint4 A = pd[0], B = pd[1];
    uint4 K = reinterpret_cast<const uint4*>(akArr)[pix];
    uint2 c2 = cfArr[pix];
    float aref = __half2float(__ushort_as_half((unsigned short)(c2.x >> 16)));
    float conf = __half2float(__ushort_as_half((unsigned short)(c2.x & 0xffffu)));
    float acc = aref * fp[0];
    acc = sample_rel(fp, A.x, (unsigned short)(K.x & 0xffffu), acc);
    acc = sample_rel(fp, A.y, (unsigned short)(K.x >> 16),     acc);
    acc = sample_rel(fp, A.z, (unsigned short)(K.y & 0xffffu), acc);
    acc = sample_rel(fp, A.w, (unsigned short)(K.y >> 16),     acc);
    acc = sample_rel(fp, B.x, (unsigned short)(K.z & 0xffffu), acc);
    acc = sample_rel(fp, B.y, (unsigned short)(K.z >> 16),     acc);
    acc = sample_rel(fp, B.z, (unsigned short)(K.w & 0xffffu), acc);
    acc = sample_rel(fp, B.w, (unsigned short)(K.w >> 16),     acc);
    float mff = __uint_as_float(c2.y);
    float km = (mff > 0.0f) ? 0.0f : 1.0f;
    float fnew = fmaf(km, acc, mff);
    fout[pix] = last ? fnew : conf * fnew;
}

extern "C" void kernel_launch(void* const* d_in, const int* in_sizes, int n_in,
                              void* d_out, int out_size, void* d_ws, size_t ws_size,
                              hipStream_t stream) {
    const float* feat_init  = (const float*)d_in[0];
    const float* guidance   = (const float*)d_in[1];
    const float* confidence = (const float*)d_in[2];
    const float* feat_fix   = (const float*)d_in[3];
    const float* aff_scale  = (const float*)d_in[4];

    // ws layout: bufA | bufB | pk1 | ak | cf | bar   (~84 MB of ~450 MiB)
    const size_t bufFloats = (size_t)NPIX + 2 * SLACK;
    float* bufA = (float*)d_ws;
    float* bufB = bufA + bufFloats;
    unsigned* pk1Arr = (unsigned*)(bufB + bufFloats);
    unsigned short* akArr = (unsigned short*)(pk1Arr + 8 * (size_t)NPIX);
    uint2* cfArr = (uint2*)(akArr + 8 * (size_t)NPIX);
    int* barPtr = (int*)(cfArr + NPIX);
    float* fA = bufA + SLACK;
    float* fB = bufB + SLACK;
    float* outp = (float*)d_out;

    // zero slack strips + barrier counter (ws is re-poisoned before each launch)
    hipMemsetAsync(bufA, 0, SLACK * sizeof(float), stream);
    hipMemsetAsync(bufA + SLACK + NPIX, 0, SLACK * sizeof(float), stream);
    hipMemsetAsync(bufB, 0, SLACK * sizeof(float), stream);
    hipMemsetAsync(bufB + SLACK + NPIX, 0, SLACK * sizeof(float), stream);
    hipMemsetAsync(barPtr, 0, 128, stream);

    precompute_kernel<<<NPIX / NTHR, NTHR, 0, stream>>>(
        feat_init, guidance, confidence, feat_fix, aff_scale,
        fA, pk1Arr, akArr, cfArr);

    // ---- primary: persistent kernel (plain launch), residency-guarded ----
    bool usePersist = false;
    {
        hipFuncAttributes fa{};
        if (hipFuncGetAttributes(&fa, reinterpret_cast<const void*>(persist_kernel))
                == hipSuccess && fa.localSizeBytes == 0) {
            int occ = 0;
            if (hipOccupancyMaxActiveBlocksPerMultiprocessor(
                    &occ, reinterpret_cast<const void*>(persist_kernel), NTHR, 0)
                    == hipSuccess) {
                int dev = 0, cu = 0;
                hipGetDevice(&dev);
                hipDeviceGetAttribute(&cu, hipDeviceAttributeMultiprocessorCount, dev);
                if ((long)occ * cu >= NBLK) usePersist = true;
            }
        }
    }
    if (usePersist) {
        persist_kernel<<<NBLK, NTHR, 0, stream>>>(
            pk1Arr, akArr, cfArr, fA, fB, outp, barPtr);
        return;
    }

    // ---- fallback: 18 compact-streamed launches ----
    for (int t = 0; t < PROP_T; ++t) {
        const float* fin = (t & 1) ? fB : fA;
        float* fout = (t == PROP_T - 1) ? outp : ((t & 1) ? fA : fB);
        step_kernel<<<NPIX / NTHR, NTHR, 0, stream>>>(
            fin, fout, pk1Arr, akArr, cfArr, (t == PROP_T - 1) ? 1 : 0);
    }
}